// Round 1
// baseline (13520.975 us; speedup 1.0000x reference)
//
#include <hip/hip_runtime.h>

#define NN 50000
#define NE 800000
#define FIN 146
#define DD 256
#define HHD 512
#define NL 25

// ---------------- helpers ----------------
__device__ __forceinline__ float wsum(float v) {
#pragma unroll
  for (int off = 32; off > 0; off >>= 1) v += __shfl_xor(v, off, 64);
  return v;
}

// ---------------- CSR build ----------------
__global__ void zero_k(int* __restrict__ p, int n) {
  int i = blockIdx.x * 256 + threadIdx.x;
  if (i < n) p[i] = 0;
}

__global__ void count_k(const int* __restrict__ ei, int* __restrict__ deg) {
  int e = blockIdx.x * 256 + threadIdx.x;
  if (e < NE) atomicAdd(&deg[ei[NE + e]], 1);
}

__global__ __launch_bounds__(1024) void scan_k(int* __restrict__ deg, int* __restrict__ rp) {
  __shared__ int buf[1024];
  __shared__ int carry;
  int tid = threadIdx.x;
  if (tid == 0) { carry = 0; rp[0] = 0; }
  __syncthreads();
  const int chunks = (NN + 1023) / 1024;
  for (int ch = 0; ch < chunks; ++ch) {
    int i = ch * 1024 + tid;
    int v = (i < NN) ? deg[i] : 0;
    buf[tid] = v;
    __syncthreads();
    int c0 = carry;
#pragma unroll
    for (int off = 1; off < 1024; off <<= 1) {
      int t = (tid >= off) ? buf[tid - off] : 0;
      __syncthreads();
      buf[tid] += t;
      __syncthreads();
    }
    if (i < NN) { rp[i + 1] = c0 + buf[tid]; deg[i] = 0; }
    __syncthreads();
    if (tid == 1023) carry = c0 + buf[1023];
    __syncthreads();
  }
}

__global__ void fill_k(const int* __restrict__ ei, const int* __restrict__ rp,
                       int* __restrict__ deg, int* __restrict__ col) {
  int e = blockIdx.x * 256 + threadIdx.x;
  if (e < NE) {
    int d = ei[NE + e];
    int pos = rp[d] + atomicAdd(&deg[d], 1);
    col[pos] = ei[e];
  }
}

// ---------------- encoder: h = xform(x) @ encW + encb ----------------
__global__ __launch_bounds__(256) void enc_k(const float* __restrict__ x,
                                             const float* __restrict__ W,
                                             const float* __restrict__ b,
                                             float* __restrict__ h) {
  __shared__ float xs[8][FIN];
  int tid = threadIdx.x;
  int row0 = blockIdx.x * 8;
#pragma unroll
  for (int r = 0; r < 8; ++r) {
    if (tid < FIN) {
      float v = x[(size_t)(row0 + r) * FIN + tid];
      if (tid >= 121) v = v * 0.01f - 0.5f;
      xs[r][tid] = v;
    }
  }
  __syncthreads();
  int c = tid;
  float acc[8];
#pragma unroll
  for (int r = 0; r < 8; ++r) acc[r] = b[c];
  for (int k = 0; k < FIN; ++k) {
    float w = W[(size_t)k * DD + c];
#pragma unroll
    for (int r = 0; r < 8; ++r) acc[r] = fmaf(xs[r][k], w, acc[r]);
  }
#pragma unroll
  for (int r = 0; r < 8; ++r) h[(size_t)(row0 + r) * DD + c] = acc[r];
}

// ---------------- z = relu(LN(h, g, b)) over D=256, one wave per row ----------------
__global__ __launch_bounds__(256) void lnrelu_k(const float* __restrict__ h,
                                                const float* __restrict__ g,
                                                const float* __restrict__ b,
                                                float* __restrict__ z) {
  int row = blockIdx.x * 4 + (threadIdx.x >> 6);
  int lane = threadIdx.x & 63;
  if (row >= NN) return;
  float4 xv = *(const float4*)(h + (size_t)row * DD + lane * 4);
  float s = xv.x + xv.y + xv.z + xv.w;
  s = wsum(s);
  float mu = s * (1.0f / DD);
  float dx = xv.x - mu, dy = xv.y - mu, dz = xv.z - mu, dw = xv.w - mu;
  float sq = dx * dx + dy * dy + dz * dz + dw * dw;
  sq = wsum(sq);
  float rstd = rsqrtf(sq * (1.0f / DD) + 1e-5f);
  float4 gv = *(const float4*)(g + lane * 4);
  float4 bv = *(const float4*)(b + lane * 4);
  float4 o;
  o.x = fmaxf(0.f, dx * rstd * gv.x + bv.x);
  o.y = fmaxf(0.f, dy * rstd * gv.y + bv.y);
  o.z = fmaxf(0.f, dz * rstd * gv.z + bv.z);
  o.w = fmaxf(0.f, dw * rstd * gv.w + bv.w);
  *(float4*)(z + (size_t)row * DD + lane * 4) = o;
}

// ---------------- softmax aggregation: hh = agg(z) + z, one wave per node ----------------
// max cancels algebraically (logit in [1e-9, ~0.1]) so single pass, no segment_max.
__global__ __launch_bounds__(256) void agg_k(const float* __restrict__ z,
                                             const int* __restrict__ rp,
                                             const int* __restrict__ col,
                                             float* __restrict__ hh) {
  int node = blockIdx.x * 4 + (threadIdx.x >> 6);
  int lane = threadIdx.x & 63;
  if (node >= NN) return;
  int beg = rp[node], end = rp[node + 1];
  float4 s = make_float4(0.f, 0.f, 0.f, 0.f);
  float4 v = make_float4(0.f, 0.f, 0.f, 0.f);
  for (int j = beg; j < end; ++j) {
    int sn = col[j];
    float4 xv = *(const float4*)(z + (size_t)sn * DD + lane * 4);
    float mx = fmaxf(xv.x, 0.f) + 1e-7f;
    float my = fmaxf(xv.y, 0.f) + 1e-7f;
    float mz = fmaxf(xv.z, 0.f) + 1e-7f;
    float mw = fmaxf(xv.w, 0.f) + 1e-7f;
    float ex = __expf(mx * 0.01f);
    float ey = __expf(my * 0.01f);
    float ez = __expf(mz * 0.01f);
    float ew = __expf(mw * 0.01f);
    s.x += ex; s.y += ey; s.z += ez; s.w += ew;
    v.x = fmaf(ex, mx, v.x);
    v.y = fmaf(ey, my, v.y);
    v.z = fmaf(ez, mz, v.z);
    v.w = fmaf(ew, mw, v.w);
  }
  float4 own = *(const float4*)(z + (size_t)node * DD + lane * 4);
  float4 o;
  o.x = v.x / (s.x + 1e-16f) + own.x;
  o.y = v.y / (s.y + 1e-16f) + own.y;
  o.z = v.z / (s.z + 1e-16f) + own.z;
  o.w = v.w / (s.w + 1e-16f) + own.w;
  *(float4*)(hh + (size_t)node * DD + lane * 4) = o;
}

// ---------------- per-row mean/rstd of mid (N x 512) ----------------
__global__ __launch_bounds__(256) void stats_k(const float* __restrict__ mid,
                                               float* __restrict__ stats) {
  int row = blockIdx.x * 4 + (threadIdx.x >> 6);
  int lane = threadIdx.x & 63;
  if (row >= NN) return;
  const float* p = mid + (size_t)row * HHD + lane * 8;
  float4 a = *(const float4*)p;
  float4 b = *(const float4*)(p + 4);
  float s = a.x + a.y + a.z + a.w + b.x + b.y + b.z + b.w;
  s = wsum(s);
  float mu = s * (1.0f / HHD);
  float d0 = a.x - mu, d1 = a.y - mu, d2 = a.z - mu, d3 = a.w - mu;
  float d4 = b.x - mu, d5 = b.y - mu, d6 = b.z - mu, d7 = b.w - mu;
  float sq = d0 * d0 + d1 * d1 + d2 * d2 + d3 * d3 + d4 * d4 + d5 * d5 + d6 * d6 + d7 * d7;
  sq = wsum(sq);
  float rstd = rsqrtf(sq * (1.0f / HHD) + 1e-5f);
  if (lane == 0) *(float2*)(stats + (size_t)row * 2) = make_float2(mu, rstd);
}

// ---------------- tiled fp32 GEMM, C[M,N] = op(A)[M,K] @ B[K,N] (+bias, opt +=C) ----------------
// TRANS=1: A-element -> relu((a - mu)*rstd*g[k] + b[k]) on LDS store (fused relu(LN))
#define BM 128
#define BN 128
#define BK 16

template <int TRANS, int ACC>
__global__ __launch_bounds__(256) void gemm_k(const float* __restrict__ A,
                                              const float* __restrict__ B,
                                              const float* __restrict__ bias,
                                              float* __restrict__ C, int M, int K, int Nfull,
                                              const float* __restrict__ stats,
                                              const float* __restrict__ lng,
                                              const float* __restrict__ lnb) {
  __shared__ float As[BK][BM + 4];
  __shared__ float Bs[BK][BN + 4];
  int tid = threadIdx.x;
  int tx = tid & 15, ty = tid >> 4;
  int bm0 = blockIdx.x * BM;
  int bn0 = blockIdx.y * BN;
  float acc[8][8];
#pragma unroll
  for (int i = 0; i < 8; i++)
#pragma unroll
    for (int j = 0; j < 8; j++) acc[i][j] = 0.f;

  for (int k0 = 0; k0 < K; k0 += BK) {
    // A tile: 128 rows x 16 k
#pragma unroll
    for (int rep = 0; rep < 2; ++rep) {
      int f = tid + rep * 256;
      int m = f >> 2, c4 = f & 3;
      int row = bm0 + m;
      float4 av;
      float2 st = make_float2(0.f, 1.f);
      if (row < M) {
        av = *(const float4*)(A + (size_t)row * K + k0 + c4 * 4);
        if (TRANS) st = *(const float2*)(stats + (size_t)row * 2);
      } else {
        av = make_float4(0.f, 0.f, 0.f, 0.f);
      }
      float vv[4] = {av.x, av.y, av.z, av.w};
#pragma unroll
      for (int j = 0; j < 4; ++j) {
        int k = c4 * 4 + j;
        float val = vv[j];
        if (TRANS) val = fmaxf(0.f, (val - st.x) * st.y * lng[k0 + k] + lnb[k0 + k]);
        As[k][m] = val;
      }
    }
    // B tile: 16 k x 128 n
#pragma unroll
    for (int rep = 0; rep < 2; ++rep) {
      int f = tid + rep * 256;
      int r = f >> 5, c = f & 31;
      float4 bv = *(const float4*)(B + (size_t)(k0 + r) * Nfull + bn0 + c * 4);
      *(float4*)&Bs[r][c * 4] = bv;
    }
    __syncthreads();
#pragma unroll
    for (int kk = 0; kk < BK; ++kk) {
      float a[8], b[8];
      *(float4*)&a[0] = *(const float4*)&As[kk][ty * 8];
      *(float4*)&a[4] = *(const float4*)&As[kk][ty * 8 + 4];
      *(float4*)&b[0] = *(const float4*)&Bs[kk][tx * 8];
      *(float4*)&b[4] = *(const float4*)&Bs[kk][tx * 8 + 4];
#pragma unroll
      for (int i = 0; i < 8; i++)
#pragma unroll
        for (int j = 0; j < 8; j++) acc[i][j] = fmaf(a[i], b[j], acc[i][j]);
    }
    __syncthreads();
  }

  float bia[8];
  *(float4*)&bia[0] = *(const float4*)(bias + bn0 + tx * 8);
  *(float4*)&bia[4] = *(const float4*)(bias + bn0 + tx * 8 + 4);
#pragma unroll
  for (int i = 0; i < 8; i++) {
    int row = bm0 + ty * 8 + i;
    if (row < M) {
      float* Cp = C + (size_t)row * Nfull + bn0 + tx * 8;
#pragma unroll
      for (int j = 0; j < 8; j += 4) {
        float4 vv;
        vv.x = acc[i][j + 0] + bia[j + 0];
        vv.y = acc[i][j + 1] + bia[j + 1];
        vv.z = acc[i][j + 2] + bia[j + 2];
        vv.w = acc[i][j + 3] + bia[j + 3];
        if (ACC) {
          float4 old = *(const float4*)(Cp + j);
          vv.x += old.x; vv.y += old.y; vv.z += old.z; vv.w += old.w;
        }
        *(float4*)(Cp + j) = vv;
      }
    }
  }
}

// ---------------- head: out = relu(relu(LN(h))@fc1 + b) @ oW + ob ----------------
__global__ __launch_bounds__(256) void final_k(const float* __restrict__ h,
                                               const float* __restrict__ rg,
                                               const float* __restrict__ rb,
                                               const float* __restrict__ fcW,
                                               const float* __restrict__ fcb,
                                               const float* __restrict__ oW,
                                               const float* __restrict__ ob,
                                               float* __restrict__ out) {
  __shared__ float zs[8][DD];
  __shared__ float ts[8][128];
  int tid = threadIdx.x;
  int w = tid >> 6, lane = tid & 63;
  int row0 = blockIdx.x * 8;
#pragma unroll
  for (int it = 0; it < 2; ++it) {
    int rl = w + it * 4;
    int row = row0 + rl;
    float4 xv = *(const float4*)(h + (size_t)row * DD + lane * 4);
    float s = xv.x + xv.y + xv.z + xv.w;
    s = wsum(s);
    float mu = s * (1.0f / DD);
    float dx = xv.x - mu, dy = xv.y - mu, dz = xv.z - mu, dw = xv.w - mu;
    float sq = dx * dx + dy * dy + dz * dz + dw * dw;
    sq = wsum(sq);
    float rstd = rsqrtf(sq * (1.0f / DD) + 1e-5f);
    float4 gv = *(const float4*)(rg + lane * 4);
    float4 bv = *(const float4*)(rb + lane * 4);
    zs[rl][lane * 4 + 0] = fmaxf(0.f, dx * rstd * gv.x + bv.x);
    zs[rl][lane * 4 + 1] = fmaxf(0.f, dy * rstd * gv.y + bv.y);
    zs[rl][lane * 4 + 2] = fmaxf(0.f, dz * rstd * gv.z + bv.z);
    zs[rl][lane * 4 + 3] = fmaxf(0.f, dw * rstd * gv.w + bv.w);
  }
  __syncthreads();
#pragma unroll
  for (int rep = 0; rep < 4; ++rep) {
    int idx = rep * 256 + tid;
    int r = idx >> 7, c = idx & 127;
    float acc = fcb[c];
#pragma unroll 4
    for (int k = 0; k < DD; ++k) acc = fmaf(zs[r][k], fcW[(size_t)k * 128 + c], acc);
    ts[r][c] = fmaxf(acc, 0.f);
  }
  __syncthreads();
  if (w == 0) {
    int r = lane >> 3, sub = lane & 7;
    float acc = 0.f;
#pragma unroll
    for (int k = sub; k < 128; k += 8) acc = fmaf(ts[r][k], oW[k], acc);
    acc += __shfl_xor(acc, 1, 64);
    acc += __shfl_xor(acc, 2, 64);
    acc += __shfl_xor(acc, 4, 64);
    if (sub == 0) out[row0 + r] = acc + ob[0];
  }
}

// ---------------- host ----------------
extern "C" void kernel_launch(void* const* d_in, const int* in_sizes, int n_in,
                              void* d_out, int out_size, void* d_ws, size_t ws_size,
                              hipStream_t stream) {
  const float* x = (const float*)d_in[0];
  const int* ei = (const int*)d_in[1];
  const float* encW = (const float*)d_in[2];
  const float* encb = (const float*)d_in[3];
  const float* cW1 = (const float*)d_in[4];
  const float* cb1 = (const float*)d_in[5];
  const float* clg = (const float*)d_in[6];
  const float* clb = (const float*)d_in[7];
  const float* cW2 = (const float*)d_in[8];
  const float* cb2 = (const float*)d_in[9];
  const float* rlg = (const float*)d_in[10];
  const float* rlb = (const float*)d_in[11];
  const float* fcW = (const float*)d_in[12];
  const float* fcb = (const float*)d_in[13];
  const float* oW = (const float*)d_in[14];
  const float* ob = (const float*)d_in[15];
  float* out = (float*)d_out;

  char* w = (char*)d_ws;
  float* h = (float*)(w);                       // 51.2 MB
  float* hh = (float*)(w + 51200000);           // 51.2 MB
  float* z = (float*)(w + 102400000);           // 51.2 MB
  float* mid = z;                               // 102.4 MB spans z + next 51.2 MB (z dead when mid live)
  float* stats = (float*)(w + 204800000);       // 0.4 MB
  int* rp = (int*)(w + 205200128);              // 200 KB
  int* deg = (int*)(w + 205400192);             // 200 KB
  int* col = (int*)(w + 205600256);             // 3.2 MB -> total ~208.8 MB

  // CSR build (per call; deterministic up to atomic fill order, FP-tolerance safe)
  zero_k<<<(NN + 255) / 256, 256, 0, stream>>>(deg, NN);
  count_k<<<(NE + 255) / 256, 256, 0, stream>>>(ei, deg);
  scan_k<<<1, 1024, 0, stream>>>(deg, rp);
  fill_k<<<(NE + 255) / 256, 256, 0, stream>>>(ei, rp, deg, col);

  enc_k<<<NN / 8, 256, 0, stream>>>(x, encW, encb, h);

  for (int l = 0; l < NL; ++l) {
    const float* zin;
    if (l == 0) {
      zin = h;
    } else {
      lnrelu_k<<<NN / 4, 256, 0, stream>>>(h, rlg + (size_t)l * DD, rlb + (size_t)l * DD, z);
      zin = z;
    }
    agg_k<<<NN / 4, 256, 0, stream>>>(zin, rp, col, hh);
    dim3 g1(391, 4);
    gemm_k<0, 0><<<g1, 256, 0, stream>>>(hh, cW1 + (size_t)l * DD * HHD, cb1 + (size_t)l * HHD,
                                         mid, NN, DD, HHD, nullptr, nullptr, nullptr);
    stats_k<<<NN / 4, 256, 0, stream>>>(mid, stats);
    dim3 g2(391, 2);
    if (l == 0) {
      gemm_k<1, 0><<<g2, 256, 0, stream>>>(mid, cW2 + (size_t)l * HHD * DD, cb2 + (size_t)l * DD,
                                           h, NN, HHD, DD, stats, clg + (size_t)l * HHD,
                                           clb + (size_t)l * HHD);
    } else {
      gemm_k<1, 1><<<g2, 256, 0, stream>>>(mid, cW2 + (size_t)l * HHD * DD, cb2 + (size_t)l * DD,
                                           h, NN, HHD, DD, stats, clg + (size_t)l * HHD,
                                           clb + (size_t)l * HHD);
    }
  }

  final_k<<<NN / 8, 256, 0, stream>>>(h, rlg, rlb, fcW, fcb, oW, ob, out);
}

// Round 2
// 9220.272 us; speedup vs baseline: 1.4664x; 1.4664x over previous
//
#include <hip/hip_runtime.h>

#define NN 50000
#define NE 800000
#define FIN 146
#define DD 256
#define HHD 512
#define NL 25

typedef __bf16 bf16x8 __attribute__((ext_vector_type(8)));
typedef float f32x4 __attribute__((ext_vector_type(4)));
typedef unsigned short us8 __attribute__((ext_vector_type(8)));

// ---------------- helpers ----------------
__device__ __forceinline__ float wsum(float v) {
#pragma unroll
  for (int off = 32; off > 0; off >>= 1) v += __shfl_xor(v, off, 64);
  return v;
}

__device__ __forceinline__ unsigned short bf16hi(float x) {
  unsigned u = __builtin_bit_cast(unsigned, x);
  u += 0x7FFF + ((u >> 16) & 1);
  return (unsigned short)(u >> 16);
}
__device__ __forceinline__ float h2f(unsigned short h) {
  unsigned u = ((unsigned)h) << 16;
  return __builtin_bit_cast(float, u);
}

// ---------------- CSR build ----------------
__global__ void zero_k(int* __restrict__ p, int n) {
  int i = blockIdx.x * 256 + threadIdx.x;
  if (i < n) p[i] = 0;
}

__global__ void count_k(const int* __restrict__ ei, int* __restrict__ deg) {
  int e = blockIdx.x * 256 + threadIdx.x;
  if (e < NE) atomicAdd(&deg[ei[NE + e]], 1);
}

__global__ __launch_bounds__(1024) void scan_k(int* __restrict__ deg, int* __restrict__ rp) {
  __shared__ int buf[1024];
  __shared__ int carry;
  int tid = threadIdx.x;
  if (tid == 0) { carry = 0; rp[0] = 0; }
  __syncthreads();
  const int chunks = (NN + 1023) / 1024;
  for (int ch = 0; ch < chunks; ++ch) {
    int i = ch * 1024 + tid;
    int v = (i < NN) ? deg[i] : 0;
    buf[tid] = v;
    __syncthreads();
    int c0 = carry;
#pragma unroll
    for (int off = 1; off < 1024; off <<= 1) {
      int t = (tid >= off) ? buf[tid - off] : 0;
      __syncthreads();
      buf[tid] += t;
      __syncthreads();
    }
    if (i < NN) { rp[i + 1] = c0 + buf[tid]; deg[i] = 0; }
    __syncthreads();
    if (tid == 1023) carry = c0 + buf[1023];
    __syncthreads();
  }
}

__global__ void fill_k(const int* __restrict__ ei, const int* __restrict__ rp,
                       int* __restrict__ deg, int* __restrict__ col) {
  int e = blockIdx.x * 256 + threadIdx.x;
  if (e < NE) {
    int d = ei[NE + e];
    int pos = rp[d] + atomicAdd(&deg[d], 1);
    col[pos] = ei[e];
  }
}

// ---------------- weight transpose + bf16 hi/lo split ----------------
// z<50: layer l=z>>1, which=z&1 (0: W1 256x512 -> [512][256], 1: W2 512x256 -> [256][512])
// z==50: fc1 256x128 -> [128][256]
__global__ __launch_bounds__(256) void wconv_k(const float* __restrict__ cW1,
                                               const float* __restrict__ cW2,
                                               const float* __restrict__ fcW,
                                               unsigned short* __restrict__ wbuf,
                                               unsigned short* __restrict__ fc1t) {
  int z = blockIdx.z;
  const float* W;
  unsigned short *oh, *ol;
  int K, N;
  if (z < 50) {
    int l = z >> 1, which = z & 1;
    if (which == 0) { W = cW1 + (size_t)l * 131072; K = 256; N = 512; oh = wbuf + (size_t)l * 524288; }
    else            { W = cW2 + (size_t)l * 131072; K = 512; N = 256; oh = wbuf + (size_t)l * 524288 + 262144; }
    ol = oh + 131072;
  } else {
    W = fcW; K = 256; N = 128; oh = fc1t; ol = oh + 32768;
  }
  if ((int)blockIdx.x >= (K >> 5) || (int)blockIdx.y >= (N >> 5)) return;
  __shared__ float tile[32][33];
  int tx = threadIdx.x, ty = threadIdx.y;
  int k0 = blockIdx.x * 32, n0 = blockIdx.y * 32;
#pragma unroll
  for (int i = 0; i < 4; ++i) {
    int r = ty + i * 8;
    tile[r][tx] = W[(size_t)(k0 + r) * N + n0 + tx];
  }
  __syncthreads();
#pragma unroll
  for (int i = 0; i < 4; ++i) {
    int r = ty + i * 8;
    float v = tile[tx][r];  // = W[k0+tx][n0+r]
    unsigned short h = bf16hi(v);
    unsigned short lo = bf16hi(v - h2f(h));
    size_t o = (size_t)(n0 + r) * K + k0 + tx;
    oh[o] = h;
    ol[o] = lo;
  }
}

// ---------------- encoder ----------------
__global__ __launch_bounds__(256) void enc_k(const float* __restrict__ x,
                                             const float* __restrict__ W,
                                             const float* __restrict__ b,
                                             float* __restrict__ h) {
  __shared__ float xs[8][FIN];
  int tid = threadIdx.x;
  int row0 = blockIdx.x * 8;
#pragma unroll
  for (int r = 0; r < 8; ++r) {
    if (tid < FIN) {
      float v = x[(size_t)(row0 + r) * FIN + tid];
      if (tid >= 121) v = v * 0.01f - 0.5f;
      xs[r][tid] = v;
    }
  }
  __syncthreads();
  int c = tid;
  float acc[8];
#pragma unroll
  for (int r = 0; r < 8; ++r) acc[r] = b[c];
  for (int k = 0; k < FIN; ++k) {
    float w = W[(size_t)k * DD + c];
#pragma unroll
    for (int r = 0; r < 8; ++r) acc[r] = fmaf(xs[r][k], w, acc[r]);
  }
#pragma unroll
  for (int r = 0; r < 8; ++r) h[(size_t)(row0 + r) * DD + c] = acc[r];
}

// ---------------- z = relu(LN(h, g, b)) ----------------
__global__ __launch_bounds__(256) void lnrelu_k(const float* __restrict__ h,
                                                const float* __restrict__ g,
                                                const float* __restrict__ b,
                                                float* __restrict__ z) {
  int row = blockIdx.x * 4 + (threadIdx.x >> 6);
  int lane = threadIdx.x & 63;
  if (row >= NN) return;
  float4 xv = *(const float4*)(h + (size_t)row * DD + lane * 4);
  float s = xv.x + xv.y + xv.z + xv.w;
  s = wsum(s);
  float mu = s * (1.0f / DD);
  float dx = xv.x - mu, dy = xv.y - mu, dz = xv.z - mu, dw = xv.w - mu;
  float sq = dx * dx + dy * dy + dz * dz + dw * dw;
  sq = wsum(sq);
  float rstd = rsqrtf(sq * (1.0f / DD) + 1e-5f);
  float4 gv = *(const float4*)(g + lane * 4);
  float4 bv = *(const float4*)(b + lane * 4);
  float4 o;
  o.x = fmaxf(0.f, dx * rstd * gv.x + bv.x);
  o.y = fmaxf(0.f, dy * rstd * gv.y + bv.y);
  o.z = fmaxf(0.f, dz * rstd * gv.z + bv.z);
  o.w = fmaxf(0.f, dw * rstd * gv.w + bv.w);
  *(float4*)(z + (size_t)row * DD + lane * 4) = o;
}

// ---------------- softmax aggregation (max cancels; single pass) ----------------
__global__ __launch_bounds__(256) void agg_k(const float* __restrict__ z,
                                             const int* __restrict__ rp,
                                             const int* __restrict__ col,
                                             float* __restrict__ hh) {
  int node = blockIdx.x * 4 + (threadIdx.x >> 6);
  int lane = threadIdx.x & 63;
  if (node >= NN) return;
  int beg = rp[node], end = rp[node + 1];
  float4 s = make_float4(0.f, 0.f, 0.f, 0.f);
  float4 v = make_float4(0.f, 0.f, 0.f, 0.f);
  for (int j = beg; j < end; ++j) {
    int sn = col[j];
    float4 xv = *(const float4*)(z + (size_t)sn * DD + lane * 4);
    float mx = fmaxf(xv.x, 0.f) + 1e-7f;
    float my = fmaxf(xv.y, 0.f) + 1e-7f;
    float mz = fmaxf(xv.z, 0.f) + 1e-7f;
    float mw = fmaxf(xv.w, 0.f) + 1e-7f;
    float ex = __expf(mx * 0.01f);
    float ey = __expf(my * 0.01f);
    float ez = __expf(mz * 0.01f);
    float ew = __expf(mw * 0.01f);
    s.x += ex; s.y += ey; s.z += ez; s.w += ew;
    v.x = fmaf(ex, mx, v.x);
    v.y = fmaf(ey, my, v.y);
    v.z = fmaf(ez, mz, v.z);
    v.w = fmaf(ew, mw, v.w);
  }
  float4 own = *(const float4*)(z + (size_t)node * DD + lane * 4);
  float4 o;
  o.x = v.x / (s.x + 1e-16f) + own.x;
  o.y = v.y / (s.y + 1e-16f) + own.y;
  o.z = v.z / (s.z + 1e-16f) + own.z;
  o.w = v.w / (s.w + 1e-16f) + own.w;
  *(float4*)(hh + (size_t)node * DD + lane * 4) = o;
}

// ---------------- per-row mean/rstd of mid (N x 512) ----------------
__global__ __launch_bounds__(256) void stats_k(const float* __restrict__ mid,
                                               float* __restrict__ stats) {
  int row = blockIdx.x * 4 + (threadIdx.x >> 6);
  int lane = threadIdx.x & 63;
  if (row >= NN) return;
  const float* p = mid + (size_t)row * HHD + lane * 8;
  float4 a = *(const float4*)p;
  float4 b = *(const float4*)(p + 4);
  float s = a.x + a.y + a.z + a.w + b.x + b.y + b.z + b.w;
  s = wsum(s);
  float mu = s * (1.0f / HHD);
  float d0 = a.x - mu, d1 = a.y - mu, d2 = a.z - mu, d3 = a.w - mu;
  float d4 = b.x - mu, d5 = b.y - mu, d6 = b.z - mu, d7 = b.w - mu;
  float sq = d0 * d0 + d1 * d1 + d2 * d2 + d3 * d3 + d4 * d4 + d5 * d5 + d6 * d6 + d7 * d7;
  sq = wsum(sq);
  float rstd = rsqrtf(sq * (1.0f / HHD) + 1e-5f);
  if (lane == 0) *(float2*)(stats + (size_t)row * 2) = make_float2(mu, rstd);
}

// ---------------- MFMA bf16 split GEMM: C[M,N] = f(A)[M,K] @ B[K,N] (+bias, opt +=C, opt relu)
// A fp32 row-major, split to bf16 hi/lo during LDS staging.
// B pre-transposed+split: BTh/BTl are [N][K] bf16 (row-major in N).
// TRANS=1: A-element -> relu((a-mu)*rstd*g[k]+b[k]) fused in staging.
template <int TRANS, int ACC, int RELU>
__global__ __launch_bounds__(256) void mgemm_k(const float* __restrict__ A,
                                               const unsigned short* __restrict__ BTh,
                                               const unsigned short* __restrict__ BTl,
                                               const float* __restrict__ bias,
                                               float* __restrict__ C, int M, int K, int N,
                                               const float* __restrict__ stats,
                                               const float* __restrict__ lng,
                                               const float* __restrict__ lnb) {
  __shared__ __align__(16) unsigned short Ash[4096], Asl[4096], Bsh[4096], Bsl[4096];
  int tid = threadIdx.x;
  int bm0 = blockIdx.x * 128, bn0 = blockIdx.y * 128;
  int lane = tid & 63, wv = tid >> 6;
  int wr = (wv >> 1) * 64, wc = (wv & 1) * 64;
  int lr = lane & 15, lc = lane >> 4;
  f32x4 acc[4][4];
  f32x4 zf = {0.f, 0.f, 0.f, 0.f};
#pragma unroll
  for (int mi = 0; mi < 4; ++mi)
#pragma unroll
    for (int ni = 0; ni < 4; ++ni) acc[mi][ni] = zf;

  int sr = tid >> 1, hf = tid & 1;       // A staging: row, half
  int barr = tid >> 7, bn = tid & 127;   // B staging: hi/lo array, row

  for (int k0 = 0; k0 < K; k0 += 32) {
    // ---- stage A (fp32 -> hi/lo bf16, optional fused relu(LN))
    {
      int row = bm0 + sr;
      float v[16];
      if (row < M) {
        const float* ap = A + (size_t)row * K + k0 + hf * 16;
        *(float4*)&v[0] = *(const float4*)(ap);
        *(float4*)&v[4] = *(const float4*)(ap + 4);
        *(float4*)&v[8] = *(const float4*)(ap + 8);
        *(float4*)&v[12] = *(const float4*)(ap + 12);
        if (TRANS) {
          float2 st = *(const float2*)(stats + (size_t)row * 2);
          const float* gp = lng + k0 + hf * 16;
          const float* bp = lnb + k0 + hf * 16;
#pragma unroll
          for (int j = 0; j < 16; ++j)
            v[j] = fmaxf(0.f, (v[j] - st.x) * st.y * gp[j] + bp[j]);
        }
      } else {
#pragma unroll
        for (int j = 0; j < 16; ++j) v[j] = 0.f;
      }
      unsigned short hi[16], lo[16];
#pragma unroll
      for (int j = 0; j < 16; ++j) {
        unsigned short hb = bf16hi(v[j]);
        hi[j] = hb;
        lo[j] = bf16hi(v[j] - h2f(hb));
      }
      int c0 = hf * 2;
      int s0 = ((c0 ^ (sr & 3)) * 8), s1 = (((c0 + 1) ^ (sr & 3)) * 8);
      *(us8*)&Ash[sr * 32 + s0] = *(us8*)&hi[0];
      *(us8*)&Ash[sr * 32 + s1] = *(us8*)&hi[8];
      *(us8*)&Asl[sr * 32 + s0] = *(us8*)&lo[0];
      *(us8*)&Asl[sr * 32 + s1] = *(us8*)&lo[8];
    }
    // ---- stage B (pre-split bf16, [N][K] layout)
    {
      const unsigned short* src = (barr ? BTl : BTh) + (size_t)(bn0 + bn) * K + k0;
      unsigned short* dst = barr ? Bsl : Bsh;
#pragma unroll
      for (int c = 0; c < 4; ++c) {
        *(us8*)&dst[bn * 32 + ((c ^ (bn & 3)) * 8)] = *(const us8*)&src[c * 8];
      }
    }
    __syncthreads();
    // ---- fragments + MFMA (3-term split)
    bf16x8 ah[4], al[4], bh[4], bl[4];
#pragma unroll
    for (int mi = 0; mi < 4; ++mi) {
      int r = wr + mi * 16 + lr;
      int off = r * 32 + ((lc ^ (r & 3)) * 8);
      ah[mi] = *(const bf16x8*)&Ash[off];
      al[mi] = *(const bf16x8*)&Asl[off];
    }
#pragma unroll
    for (int ni = 0; ni < 4; ++ni) {
      int n = wc + ni * 16 + lr;
      int off = n * 32 + ((lc ^ (n & 3)) * 8);
      bh[ni] = *(const bf16x8*)&Bsh[off];
      bl[ni] = *(const bf16x8*)&Bsl[off];
    }
#pragma unroll
    for (int mi = 0; mi < 4; ++mi)
#pragma unroll
      for (int ni = 0; ni < 4; ++ni) {
        acc[mi][ni] = __builtin_amdgcn_mfma_f32_16x16x32_bf16(ah[mi], bh[ni], acc[mi][ni], 0, 0, 0);
        acc[mi][ni] = __builtin_amdgcn_mfma_f32_16x16x32_bf16(ah[mi], bl[ni], acc[mi][ni], 0, 0, 0);
        acc[mi][ni] = __builtin_amdgcn_mfma_f32_16x16x32_bf16(al[mi], bh[ni], acc[mi][ni], 0, 0, 0);
      }
    __syncthreads();
  }
  // ---- epilogue
#pragma unroll
  for (int ni = 0; ni < 4; ++ni) {
    int colg = bn0 + wc + ni * 16 + lr;
    float bia = bias[colg];
#pragma unroll
    for (int mi = 0; mi < 4; ++mi) {
#pragma unroll
      for (int r = 0; r < 4; ++r) {
        int row = bm0 + wr + mi * 16 + lc * 4 + r;
        if (row < M) {
          float vv = acc[mi][ni][r] + bia;
          if (ACC) vv += C[(size_t)row * N + colg];
          if (RELU) vv = fmaxf(vv, 0.f);
          C[(size_t)row * N + colg] = vv;
        }
      }
    }
  }
}

// ---------------- out matvec: out[i] = t1[i,:] . oW + ob ----------------
__global__ __launch_bounds__(256) void outmv_k(const float* __restrict__ t1,
                                               const float* __restrict__ oW,
                                               const float* __restrict__ ob,
                                               float* __restrict__ out) {
  int row = blockIdx.x * 4 + (threadIdx.x >> 6);
  int lane = threadIdx.x & 63;
  if (row >= NN) return;
  float2 v = *(const float2*)(t1 + (size_t)row * 128 + lane * 2);
  float2 w = *(const float2*)(oW + lane * 2);
  float s = v.x * w.x + v.y * w.y;
  s = wsum(s);
  if (lane == 0) out[row] = s + ob[0];
}

// ---------------- host ----------------
extern "C" void kernel_launch(void* const* d_in, const int* in_sizes, int n_in,
                              void* d_out, int out_size, void* d_ws, size_t ws_size,
                              hipStream_t stream) {
  const float* x = (const float*)d_in[0];
  const int* ei = (const int*)d_in[1];
  const float* encW = (const float*)d_in[2];
  const float* encb = (const float*)d_in[3];
  const float* cW1 = (const float*)d_in[4];
  const float* cb1 = (const float*)d_in[5];
  const float* clg = (const float*)d_in[6];
  const float* clb = (const float*)d_in[7];
  const float* cW2 = (const float*)d_in[8];
  const float* cb2 = (const float*)d_in[9];
  const float* rlg = (const float*)d_in[10];
  const float* rlb = (const float*)d_in[11];
  const float* fcW = (const float*)d_in[12];
  const float* fcb = (const float*)d_in[13];
  const float* oW = (const float*)d_in[14];
  const float* ob = (const float*)d_in[15];
  float* out = (float*)d_out;

  char* w = (char*)d_ws;
  float* h = (float*)(w);                            // 51.2 MB
  float* hh = (float*)(w + 51200000);                // 51.2 MB
  float* z = (float*)(w + 102400000);                // 51.2 MB
  float* mid = z;                                    // spans 102.4MB..204.8MB (z dead when mid live)
  float* t1 = (float*)(w + 153600000);               // 25.6 MB (head phase only; mid dead)
  float* stats = (float*)(w + 204800000);            // 0.4 MB
  int* rp = (int*)(w + 205200128);
  int* deg = (int*)(w + 205400192);
  int* col = (int*)(w + 205600256);                  // 3.2 MB
  unsigned short* wbuf = (unsigned short*)(w + 208800256);  // 26.2 MB
  unsigned short* fc1t = (unsigned short*)(w + 235014656);  // 131 KB

  // CSR build
  zero_k<<<(NN + 255) / 256, 256, 0, stream>>>(deg, NN);
  count_k<<<(NE + 255) / 256, 256, 0, stream>>>(ei, deg);
  scan_k<<<1, 1024, 0, stream>>>(deg, rp);
  fill_k<<<(NE + 255) / 256, 256, 0, stream>>>(ei, rp, deg, col);

  // weight transpose + split (once per launch)
  wconv_k<<<dim3(16, 16, 51), dim3(32, 8), 0, stream>>>(cW1, cW2, fcW, wbuf, fc1t);

  enc_k<<<NN / 8, 256, 0, stream>>>(x, encW, encb, h);

  for (int l = 0; l < NL; ++l) {
    const float* zin;
    if (l == 0) {
      zin = h;
    } else {
      lnrelu_k<<<NN / 4, 256, 0, stream>>>(h, rlg + (size_t)l * DD, rlb + (size_t)l * DD, z);
      zin = z;
    }
    agg_k<<<NN / 4, 256, 0, stream>>>(zin, rp, col, hh);

    const unsigned short* w1h = wbuf + (size_t)l * 524288;
    mgemm_k<0, 0, 0><<<dim3(391, 4), 256, 0, stream>>>(
        hh, w1h, w1h + 131072, cb1 + (size_t)l * HHD, mid, NN, DD, HHD,
        nullptr, nullptr, nullptr);
    stats_k<<<NN / 4, 256, 0, stream>>>(mid, stats);
    const unsigned short* w2h = wbuf + (size_t)l * 524288 + 262144;
    if (l == 0) {
      mgemm_k<1, 0, 0><<<dim3(391, 2), 256, 0, stream>>>(
          mid, w2h, w2h + 131072, cb2 + (size_t)l * DD, h, NN, HHD, DD,
          stats, clg + (size_t)l * HHD, clb + (size_t)l * HHD);
    } else {
      mgemm_k<1, 1, 0><<<dim3(391, 2), 256, 0, stream>>>(
          mid, w2h, w2h + 131072, cb2 + (size_t)l * DD, h, NN, HHD, DD,
          stats, clg + (size_t)l * HHD, clb + (size_t)l * HHD);
    }
  }

  // head: z = relu(LN(h, rlg0, rlb0)); t1 = relu(z @ fc1 + b); out = t1 @ oW + ob
  lnrelu_k<<<NN / 4, 256, 0, stream>>>(h, rlg, rlb, z);
  mgemm_k<0, 0, 1><<<dim3(391, 1), 256, 0, stream>>>(
      z, fc1t, fc1t + 32768, fcb, t1, NN, DD, 128, nullptr, nullptr, nullptr);
  outmv_k<<<NN / 4, 256, 0, stream>>>(t1, oW, ob, out);
}